// Round 5
// baseline (24.145 us; speedup 1.0000x reference)
//
#include <hip/hip_runtime.h>
#include <math.h>

#ifndef __has_builtin
#define __has_builtin(x) 0
#endif

__device__ __forceinline__ float fexp2(float v) {
#if __has_builtin(__builtin_amdgcn_exp2f)
  return __builtin_amdgcn_exp2f(v);
#else
  return exp2f(v);
#endif
}

constexpr int Bc  = 8;
constexpr int Nc  = 512;
constexpr int Mc  = 2048;
constexpr int CIN = 8;
constexpr int Cc  = 9;      // 1 + CIN
constexpr int Oc  = 64;

constexpr int T   = 512;    // threads/block (8 waves)
constexpr int G   = 16;     // m-pair groups per wave (MT=2 -> 32 m per block)
constexpr int S   = 32;     // n-slices total (4 in-wave x 8 waves)
constexpr int NSL = Nc / S; // 16 n per slice
constexpr int MB  = 2 * G;  // 32 m per block
// grid = Bc*(Mc/MB) = 512 blocks -> 2 blocks/CU, 4 waves/SIMD

__global__ __launch_bounds__(T, 4) void fused(
    const float* __restrict__ xg, const float* __restrict__ yg,
    const float* __restrict__ tg, const float* __restrict__ sg,
    const float* __restrict__ Wg, const float* __restrict__ bg,
    float* __restrict__ outg)
{
  __shared__ float2 wpart[8][Cc][G + 1];  // per-wave partials, 9.8 KB (padded)
  __shared__ float2 hh[Cc][G + 1];        // final per-(c, m-pair) sums
  __shared__ float  sW[Cc][Oc];
  __shared__ float  sb[Oc];

  const int tid  = threadIdx.x;
  const int bx   = blockIdx.x;
  const int b    = bx >> 6;
  const int m0   = (bx & 63) * MB;
  const int w    = tid >> 6;        // wave 0..7
  const int lane = tid & 63;
  const int slo  = lane & 3;        // in-wave slice 0..3
  const int g    = lane >> 2;       // m-pair group 0..15
  const int s    = (w << 2) | slo;  // global slice 0..31

  for (int i = tid; i < Cc * Oc; i += T) (&sW[0][0])[i] = Wg[i];
  if (tid < Oc) sb[tid] = bg[tid];

  // exp(-0.5 d / s_c^2) = exp2(kk_c * d)
  float kk[Cc];
  bool uni = true;
  const float s0 = sg[0];
  #pragma unroll
  for (int c = 0; c < Cc; ++c) {
    const float sv = sg[c];
    kk[c] = -0.72134752044448170f * __expf(-2.0f * sv);  // -0.5*log2(e)*e^{-2 sigma}
    uni = uni && (sv == s0);
  }

  const float t0 = tg[b * Mc + m0 + g * 2 + 0];
  const float t1 = tg[b * Mc + m0 + g * 2 + 1];

  float acc0[Cc], acc1[Cc];
  #pragma unroll
  for (int c = 0; c < Cc; ++c) { acc0[c] = 0.0f; acc1[c] = 0.0f; }

  const float*  xb = xg + b * Nc;
  const float4* yb = reinterpret_cast<const float4*>(yg + (size_t)b * Nc * CIN);

  if (uni) {
    const float q   = sqrtf(-kk[0]);
    const float tq0 = t0 * q, tq1 = t1 * q;
    #pragma unroll 4
    for (int i = 0; i < NSL; ++i) {
      const int n = s * NSL + i;
      const float xq = xb[n] * q;
      const float4 ya = yb[2 * n];
      const float4 yc = yb[2 * n + 1];
      const float yv[CIN] = {ya.x, ya.y, ya.z, ya.w, yc.x, yc.y, yc.z, yc.w};
      const float dq0 = xq - tq0;
      const float dq1 = xq - tq1;
      const float w0 = fexp2(-dq0 * dq0);
      const float w1 = fexp2(-dq1 * dq1);
      acc0[0] += w0; acc1[0] += w1;
      #pragma unroll
      for (int c = 1; c < Cc; ++c) {
        acc0[c] += yv[c - 1] * w0;
        acc1[c] += yv[c - 1] * w1;
      }
    }
  } else {
    #pragma unroll 2
    for (int i = 0; i < NSL; ++i) {
      const int n = s * NSL + i;
      const float xv = xb[n];
      const float4 ya = yb[2 * n];
      const float4 yc = yb[2 * n + 1];
      const float yv[CIN] = {ya.x, ya.y, ya.z, ya.w, yc.x, yc.y, yc.z, yc.w};
      const float d0 = xv - t0, d1 = xv - t1;
      const float d0sq = d0 * d0, d1sq = d1 * d1;
      acc0[0] += fexp2(d0sq * kk[0]);
      acc1[0] += fexp2(d1sq * kk[0]);
      #pragma unroll
      for (int c = 1; c < Cc; ++c) {
        acc0[c] += yv[c - 1] * fexp2(d0sq * kk[c]);
        acc1[c] += yv[c - 1] * fexp2(d1sq * kk[c]);
      }
    }
  }

  // in-wave reduce over the 4 slices in lane bits 0-1 (DPP shuffles, no LDS)
  #pragma unroll
  for (int off = 1; off <= 2; off <<= 1) {
    #pragma unroll
    for (int c = 0; c < Cc; ++c) {
      acc0[c] += __shfl_xor(acc0[c], off);
      acc1[c] += __shfl_xor(acc1[c], off);
    }
  }

  // one lane per (wave, m-pair) writes its 9-channel partial
  if (slo == 0) {
    #pragma unroll
    for (int c = 0; c < Cc; ++c)
      wpart[w][c][g] = make_float2(acc0[c], acc1[c]);
  }
  __syncthreads();

  // 144 threads: sum the 8 wave-partials per (c, m-pair)
  if (tid < Cc * G) {
    const int c  = tid >> 4;
    const int gg = tid & 15;
    float2 t2 = wpart[0][c][gg];
    #pragma unroll
    for (int ww = 1; ww < 8; ++ww) {
      const float2 p = wpart[ww][c][gg];
      t2.x += p.x; t2.y += p.y;
    }
    hh[c][gg] = t2;
  }
  __syncthreads();

  // epilogue: one float4 of output per thread
  const int oq = tid & 15;   // o-quad
  const int mm = tid >> 4;   // m within tile 0..31
  const int gg = mm >> 1;
  const int hf = mm & 1;

  float hv[Cc];
  #pragma unroll
  for (int c = 0; c < Cc; ++c) {
    const float2 p = hh[c][gg];
    hv[c] = hf ? p.y : p.x;
  }

  const float dens = hv[0];
  const float inv  = 1.0f / (dens + 1e-8f);
  float4 r = *reinterpret_cast<const float4*>(&sb[oq * 4]);
  {
    const float4 w0 = *reinterpret_cast<const float4*>(&sW[0][oq * 4]);
    r.x += dens * w0.x; r.y += dens * w0.y;
    r.z += dens * w0.z; r.w += dens * w0.w;
  }
  #pragma unroll
  for (int c = 1; c < Cc; ++c) {
    const float h = hv[c] * inv;
    const float4 wc = *reinterpret_cast<const float4*>(&sW[c][oq * 4]);
    r.x += h * wc.x; r.y += h * wc.y;
    r.z += h * wc.z; r.w += h * wc.w;
  }
  reinterpret_cast<float4*>(outg)[((size_t)(b * Mc + m0 + mm) * Oc + oq * 4) >> 2] = r;
}

extern "C" void kernel_launch(void* const* d_in, const int* in_sizes, int n_in,
                              void* d_out, int out_size, void* d_ws, size_t ws_size,
                              hipStream_t stream) {
  const float* x  = (const float*)d_in[0];
  const float* y  = (const float*)d_in[1];
  const float* t  = (const float*)d_in[2];
  const float* s  = (const float*)d_in[3];
  const float* W  = (const float*)d_in[4];
  const float* bb = (const float*)d_in[5];
  float* out = (float*)d_out;

  fused<<<dim3(Bc * (Mc / MB)), T, 0, stream>>>(x, y, t, s, W, bb, out);
}

// Round 6
// 13.398 us; speedup vs baseline: 1.8022x; 1.8022x over previous
//
#include <hip/hip_runtime.h>
#include <math.h>

#ifndef __has_builtin
#define __has_builtin(x) 0
#endif

__device__ __forceinline__ float fexp2(float v) {
#if __has_builtin(__builtin_amdgcn_exp2f)
  return __builtin_amdgcn_exp2f(v);
#else
  return exp2f(v);
#endif
}

constexpr int Bc  = 8;
constexpr int Nc  = 512;
constexpr int Mc  = 2048;
constexpr int CIN = 8;
constexpr int Cc  = 9;      // 1 + CIN
constexpr int Oc  = 64;

constexpr int T   = 512;    // threads/block (8 waves)
constexpr int G   = 16;     // m-pair groups (MT=2 -> 32 m per block)
constexpr int S   = 32;     // n-slices = T/G
constexpr int NSL = Nc / S; // 16 n per slice
constexpr int MB  = 2 * G;  // 32 m per block
// grid = Bc*(Mc/MB) = 512 blocks -> 2 blocks/CU, 4 waves/SIMD

__global__ __launch_bounds__(T, 4) void fused(
    const float* __restrict__ xg, const float* __restrict__ yg,
    const float* __restrict__ tg, const float* __restrict__ sg,
    const float* __restrict__ Wg, const float* __restrict__ bg,
    float* __restrict__ outg)
{
  __shared__ float2 wpart[8][Cc][G + 1];  // per-wave partials, 9.8 KB (padded)
  __shared__ float2 hh[Cc][G + 1];
  __shared__ float  sW[Cc][Oc];
  __shared__ float  sb[Oc];

  const int tid = threadIdx.x;
  const int bx  = blockIdx.x;
  const int b   = bx >> 6;
  const int m0  = (bx & 63) * MB;

  for (int i = tid; i < Cc * Oc; i += T) (&sW[0][0])[i] = Wg[i];
  if (tid < Oc) sb[tid] = bg[tid];

  // exp(-0.5 d / s_c^2) = exp2(kk_c * d)
  float kk[Cc];
  bool uni = true;
  const float s0 = sg[0];
  #pragma unroll
  for (int c = 0; c < Cc; ++c) {
    const float sv = sg[c];
    kk[c] = -0.72134752044448170f * __expf(-2.0f * sv);  // -0.5*log2(e)*e^{-2 sigma}
    uni = uni && (sv == s0);
  }

  // ---- EXACT round-4 lane mapping: 16 consecutive lanes share one slice ----
  const int g = tid & (G - 1);   // m-pair group 0..15
  const int s = tid >> 4;        // n-slice 0..31 (lane bits 4-5 + wave bits)

  const float t0 = tg[b * Mc + m0 + g * 2 + 0];
  const float t1 = tg[b * Mc + m0 + g * 2 + 1];

  float acc0[Cc], acc1[Cc];
  #pragma unroll
  for (int c = 0; c < Cc; ++c) { acc0[c] = 0.0f; acc1[c] = 0.0f; }

  const float*  xb = xg + b * Nc;
  const float4* yb = reinterpret_cast<const float4*>(yg + (size_t)b * Nc * CIN);

  if (uni) {
    const float q   = sqrtf(-kk[0]);
    const float tq0 = t0 * q, tq1 = t1 * q;
    #pragma unroll 4
    for (int i = 0; i < NSL; ++i) {
      const int n = s * NSL + i;
      const float xq = xb[n] * q;
      const float4 ya = yb[2 * n];
      const float4 yc = yb[2 * n + 1];
      const float yv[CIN] = {ya.x, ya.y, ya.z, ya.w, yc.x, yc.y, yc.z, yc.w};
      const float dq0 = xq - tq0;
      const float dq1 = xq - tq1;
      const float w0 = fexp2(-dq0 * dq0);
      const float w1 = fexp2(-dq1 * dq1);
      acc0[0] += w0; acc1[0] += w1;
      #pragma unroll
      for (int c = 1; c < Cc; ++c) {
        acc0[c] += yv[c - 1] * w0;
        acc1[c] += yv[c - 1] * w1;
      }
    }
  } else {
    #pragma unroll 2
    for (int i = 0; i < NSL; ++i) {
      const int n = s * NSL + i;
      const float xv = xb[n];
      const float4 ya = yb[2 * n];
      const float4 yc = yb[2 * n + 1];
      const float yv[CIN] = {ya.x, ya.y, ya.z, ya.w, yc.x, yc.y, yc.z, yc.w};
      const float d0 = xv - t0, d1 = xv - t1;
      const float d0sq = d0 * d0, d1sq = d1 * d1;
      acc0[0] += fexp2(d0sq * kk[0]);
      acc1[0] += fexp2(d1sq * kk[0]);
      #pragma unroll
      for (int c = 1; c < Cc; ++c) {
        acc0[c] += yv[c - 1] * fexp2(d0sq * kk[c]);
        acc1[c] += yv[c - 1] * fexp2(d1sq * kk[c]);
      }
    }
  }

  // in-wave reduce over the 4 slices held in lane bits 4-5 (xor 16, 32)
  #pragma unroll
  for (int off = 16; off <= 32; off <<= 1) {
    #pragma unroll
    for (int c = 0; c < Cc; ++c) {
      acc0[c] += __shfl_xor(acc0[c], off);
      acc1[c] += __shfl_xor(acc1[c], off);
    }
  }

  // lanes 0..15 of each wave hold the wave-total for their g
  const int w    = tid >> 6;
  const int lane = tid & 63;
  if (lane < G) {
    #pragma unroll
    for (int c = 0; c < Cc; ++c)
      wpart[w][c][g] = make_float2(acc0[c], acc1[c]);
  }
  __syncthreads();

  // 144 threads: sum the 8 wave-partials per (c, m-pair)
  if (tid < Cc * G) {
    const int c  = tid >> 4;
    const int gg = tid & 15;
    float2 t2 = wpart[0][c][gg];
    #pragma unroll
    for (int ww = 1; ww < 8; ++ww) {
      const float2 p = wpart[ww][c][gg];
      t2.x += p.x; t2.y += p.y;
    }
    hh[c][gg] = t2;
  }
  __syncthreads();

  // epilogue: one float4 of output per thread (identical to round 4)
  const int oq = tid & 15;   // o-quad
  const int mm = tid >> 4;   // m within tile 0..31
  const int gg = mm >> 1;
  const int hf = mm & 1;

  float hv[Cc];
  #pragma unroll
  for (int c = 0; c < Cc; ++c) {
    const float2 p = hh[c][gg];
    hv[c] = hf ? p.y : p.x;
  }

  const float dens = hv[0];
  const float inv  = 1.0f / (dens + 1e-8f);
  float4 r = *reinterpret_cast<const float4*>(&sb[oq * 4]);
  {
    const float4 w0 = *reinterpret_cast<const float4*>(&sW[0][oq * 4]);
    r.x += dens * w0.x; r.y += dens * w0.y;
    r.z += dens * w0.z; r.w += dens * w0.w;
  }
  #pragma unroll
  for (int c = 1; c < Cc; ++c) {
    const float h = hv[c] * inv;
    const float4 wc = *reinterpret_cast<const float4*>(&sW[c][oq * 4]);
    r.x += h * wc.x; r.y += h * wc.y;
    r.z += h * wc.z; r.w += h * wc.w;
  }
  reinterpret_cast<float4*>(outg)[((size_t)(b * Mc + m0 + mm) * Oc + oq * 4) >> 2] = r;
}

extern "C" void kernel_launch(void* const* d_in, const int* in_sizes, int n_in,
                              void* d_out, int out_size, void* d_ws, size_t ws_size,
                              hipStream_t stream) {
  const float* x  = (const float*)d_in[0];
  const float* y  = (const float*)d_in[1];
  const float* t  = (const float*)d_in[2];
  const float* s  = (const float*)d_in[3];
  const float* W  = (const float*)d_in[4];
  const float* bb = (const float*)d_in[5];
  float* out = (float*)d_out;

  fused<<<dim3(Bc * (Mc / MB)), T, 0, stream>>>(x, y, t, s, W, bb, out);
}

// Round 7
// 12.545 us; speedup vs baseline: 1.9247x; 1.0680x over previous
//
#include <hip/hip_runtime.h>
#include <math.h>

#ifndef __has_builtin
#define __has_builtin(x) 0
#endif

__device__ __forceinline__ float fexp2(float v) {
#if __has_builtin(__builtin_amdgcn_exp2f)
  return __builtin_amdgcn_exp2f(v);
#else
  return exp2f(v);
#endif
}

typedef float v2f __attribute__((ext_vector_type(2)));

constexpr int Bc  = 8;
constexpr int Nc  = 512;
constexpr int Mc  = 2048;
constexpr int CIN = 8;
constexpr int Cc  = 9;      // 1 + CIN
constexpr int Oc  = 64;

constexpr int T   = 512;    // threads/block (8 waves)
constexpr int G   = 16;     // m-pair groups (MT=2 -> 32 m per block)
constexpr int S   = 32;     // n-slices = T/G
constexpr int NSL = Nc / S; // 16 n per slice
constexpr int MB  = 2 * G;  // 32 m per block
// grid = Bc*(Mc/MB) = 512 blocks -> 2 blocks/CU, 4 waves/SIMD

__global__ __launch_bounds__(T, 4) void fused(
    const float* __restrict__ xg, const float* __restrict__ yg,
    const float* __restrict__ tg, const float* __restrict__ sg,
    const float* __restrict__ Wg, const float* __restrict__ bg,
    float* __restrict__ outg)
{
  __shared__ float2 wpart[8][Cc][G + 1];  // per-wave partials, 9.8 KB (padded)
  __shared__ float2 hh[Cc][G + 1];
  __shared__ float  sW[Cc][Oc];
  __shared__ float  sb[Oc];

  const int tid = threadIdx.x;
  const int bx  = blockIdx.x;
  const int b   = bx >> 6;
  const int m0  = (bx & 63) * MB;

  // start the sigma cold-miss as early as possible
  const float4 sv0 = *reinterpret_cast<const float4*>(sg);
  const float4 sv1 = *reinterpret_cast<const float4*>(sg + 4);
  const float  sv8 = sg[8];

  // round-4 lane mapping: 16 consecutive lanes share one slice (broadcast loads)
  const int g = tid & (G - 1);   // m-pair group 0..15
  const int s = tid >> 4;        // n-slice 0..31

  const float t0 = tg[b * Mc + m0 + g * 2 + 0];
  const float t1 = tg[b * Mc + m0 + g * 2 + 1];

  for (int i = tid; i < Cc * Oc; i += T) (&sW[0][0])[i] = Wg[i];
  if (tid < Oc) sb[tid] = bg[tid];

  // exp(-0.5 d / s_c^2) = exp2(kk_c * d)
  const float sa[Cc] = {sv0.x, sv0.y, sv0.z, sv0.w, sv1.x, sv1.y, sv1.z, sv1.w, sv8};
  float kk[Cc];
  bool uni = true;
  #pragma unroll
  for (int c = 0; c < Cc; ++c) {
    kk[c] = -0.72134752044448170f * __expf(-2.0f * sa[c]);  // -0.5*log2(e)*e^{-2 sigma}
    uni = uni && (sa[c] == sa[0]);
  }

  v2f acc[Cc];
  #pragma unroll
  for (int c = 0; c < Cc; ++c) acc[c] = (v2f){0.0f, 0.0f};

  const float*  xb = xg + b * Nc;
  const float4* yb = reinterpret_cast<const float4*>(yg + (size_t)b * Nc * CIN);

  if (uni) {
    const float q    = sqrtf(-kk[0]);
    const v2f   tq01 = {t0 * q, t1 * q};
    #pragma unroll 4
    for (int i = 0; i < NSL; ++i) {
      const int n = s * NSL + i;
      const float xq = xb[n] * q;
      const float4 ya = yb[2 * n];
      const float4 yc = yb[2 * n + 1];
      const float yv[CIN] = {ya.x, ya.y, ya.z, ya.w, yc.x, yc.y, yc.z, yc.w};
      const v2f dq  = (v2f){xq, xq} - tq01;   // v_pk_add (neg)
      const v2f nd2 = -(dq * dq);             // v_pk_mul + neg
      const v2f w01 = {fexp2(nd2.x), fexp2(nd2.y)};
      acc[0] += w01;                          // v_pk_add
      #pragma unroll
      for (int c = 1; c < Cc; ++c)
        acc[c] += w01 * yv[c - 1];            // v_pk_fma, scalar splat
    }
  } else {
    #pragma unroll 2
    for (int i = 0; i < NSL; ++i) {
      const int n = s * NSL + i;
      const float xv = xb[n];
      const float4 ya = yb[2 * n];
      const float4 yc = yb[2 * n + 1];
      const float yv[CIN] = {ya.x, ya.y, ya.z, ya.w, yc.x, yc.y, yc.z, yc.w};
      const float d0 = xv - t0, d1 = xv - t1;
      const float d0sq = d0 * d0, d1sq = d1 * d1;
      acc[0] += (v2f){fexp2(d0sq * kk[0]), fexp2(d1sq * kk[0])};
      #pragma unroll
      for (int c = 1; c < Cc; ++c)
        acc[c] += (v2f){yv[c - 1] * fexp2(d0sq * kk[c]),
                        yv[c - 1] * fexp2(d1sq * kk[c])};
    }
  }

  // in-wave reduce over the 4 slices in lane bits 4-5 (xor 16, 32)
  #pragma unroll
  for (int off = 16; off <= 32; off <<= 1) {
    #pragma unroll
    for (int c = 0; c < Cc; ++c) {
      acc[c].x += __shfl_xor(acc[c].x, off);
      acc[c].y += __shfl_xor(acc[c].y, off);
    }
  }

  const int w    = tid >> 6;
  const int lane = tid & 63;
  if (lane < G) {
    #pragma unroll
    for (int c = 0; c < Cc; ++c)
      wpart[w][c][g] = make_float2(acc[c].x, acc[c].y);
  }
  __syncthreads();

  // 144 threads: sum the 8 wave-partials per (c, m-pair)
  if (tid < Cc * G) {
    const int c  = tid >> 4;
    const int gg = tid & 15;
    float2 t2 = wpart[0][c][gg];
    #pragma unroll
    for (int ww = 1; ww < 8; ++ww) {
      const float2 p = wpart[ww][c][gg];
      t2.x += p.x; t2.y += p.y;
    }
    hh[c][gg] = t2;
  }
  __syncthreads();

  // epilogue: one float4 of output per thread
  const int oq = tid & 15;   // o-quad
  const int mm = tid >> 4;   // m within tile 0..31
  const int gg = mm >> 1;
  const int hf = mm & 1;

  float hv[Cc];
  #pragma unroll
  for (int c = 0; c < Cc; ++c) {
    const float2 p = hh[c][gg];
    hv[c] = hf ? p.y : p.x;
  }

  const float dens = hv[0];
  const float inv  = 1.0f / (dens + 1e-8f);
  float4 r = *reinterpret_cast<const float4*>(&sb[oq * 4]);
  {
    const float4 w0 = *reinterpret_cast<const float4*>(&sW[0][oq * 4]);
    r.x += dens * w0.x; r.y += dens * w0.y;
    r.z += dens * w0.z; r.w += dens * w0.w;
  }
  #pragma unroll
  for (int c = 1; c < Cc; ++c) {
    const float h = hv[c] * inv;
    const float4 wc = *reinterpret_cast<const float4*>(&sW[c][oq * 4]);
    r.x += h * wc.x; r.y += h * wc.y;
    r.z += h * wc.z; r.w += h * wc.w;
  }
  reinterpret_cast<float4*>(outg)[((size_t)(b * Mc + m0 + mm) * Oc + oq * 4) >> 2] = r;
}

extern "C" void kernel_launch(void* const* d_in, const int* in_sizes, int n_in,
                              void* d_out, int out_size, void* d_ws, size_t ws_size,
                              hipStream_t stream) {
  const float* x  = (const float*)d_in[0];
  const float* y  = (const float*)d_in[1];
  const float* t  = (const float*)d_in[2];
  const float* s  = (const float*)d_in[3];
  const float* W  = (const float*)d_in[4];
  const float* bb = (const float*)d_in[5];
  float* out = (float*)d_out;

  fused<<<dim3(Bc * (Mc / MB)), T, 0, stream>>>(x, y, t, s, W, bb, out);
}